// Round 4
// baseline (621.181 us; speedup 1.0000x reference)
//
#include <hip/hip_runtime.h>
#include <hip/hip_bf16.h>

#define N_NODES 100000
#define N_EDGES 1600000
#define IN_DIM 512
#define HID 64
#define NCLS 16
#define NB ((N_NODES + 1023) / 1024)   // scan blocks (98)

typedef __attribute__((ext_vector_type(8))) short bf16x8;
typedef __attribute__((ext_vector_type(8))) unsigned short ushort8;
typedef __attribute__((ext_vector_type(4))) float f32x4;

static __device__ __forceinline__ unsigned short f2bf(float f) {
    union { float f; unsigned int u; } v; v.f = f;
    unsigned int u = v.u;
    unsigned int r = (u + 0x7fffu + ((u >> 16) & 1u)) >> 16;
    return (unsigned short)r;
}
static __device__ __forceinline__ float bf2f(unsigned short u) {
    union { unsigned int i; float f; } v; v.i = ((unsigned int)u) << 16; return v.f;
}

// ---------- graph preprocessing ----------

__global__ void k_init(int* cnt) {
    int i = blockIdx.x * 256 + threadIdx.x;
    if (i < N_NODES) cnt[i] = 0;
}

// one atomic per edge: slot within the dst row
__global__ void k_pass1(const int* __restrict__ dst, int* cnt, int* __restrict__ li) {
    int e = blockIdx.x * 256 + threadIdx.x;
    if (e < N_EDGES) li[e] = atomicAdd(&cnt[dst[e]], 1);
}

// exclusive scan of cnt -> ptr
__global__ void k_scan1(const int* __restrict__ cnt, int* ptr, int* bsum) {
    __shared__ int s[256];
    int t = threadIdx.x;
    int i0 = blockIdx.x * 1024 + t * 4;
    int c[4];
#pragma unroll
    for (int j = 0; j < 4; j++) c[j] = (i0 + j < N_NODES) ? cnt[i0 + j] : 0;
    int sum4 = c[0] + c[1] + c[2] + c[3];
    s[t] = sum4;
    __syncthreads();
    int v = sum4;
    for (int off = 1; off < 256; off <<= 1) {
        int add = (t >= off) ? s[t - off] : 0;
        __syncthreads();
        v += add;
        s[t] = v;
        __syncthreads();
    }
    int run = v - sum4;
#pragma unroll
    for (int j = 0; j < 4; j++) {
        if (i0 + j < N_NODES) ptr[i0 + j] = run;
        run += c[j];
    }
    if (t == 255) bsum[blockIdx.x] = v;
}

__global__ void k_scan2(int* bsum, int* ptr) {
    __shared__ int s[128];
    int t = threadIdx.x;
    int val = (t < NB) ? bsum[t] : 0;
    s[t] = val;
    __syncthreads();
    int v = val;
    for (int off = 1; off < 128; off <<= 1) {
        int add = (t >= off) ? s[t - off] : 0;
        __syncthreads();
        v += add;
        s[t] = v;
        __syncthreads();
    }
    if (t < NB) bsum[t] = v - val;
    if (t == 0) ptr[N_NODES] = N_EDGES;
}

__global__ void k_scan3(int* ptr, const int* __restrict__ bsum) {
    int t = threadIdx.x;
    int i0 = blockIdx.x * 1024 + t * 4;
    int add = bsum[blockIdx.x];
#pragma unroll
    for (int j = 0; j < 4; j++)
        if (i0 + j < N_NODES) ptr[i0 + j] += add;
}

// atomic-free scatter: position = ptr[dst] + li[e]; csr_w holds RAW w
__global__ void k_pass2(const int* __restrict__ src, const int* __restrict__ dst,
                        const float* __restrict__ w, const int* __restrict__ ptr,
                        const int* __restrict__ li,
                        int* __restrict__ csr_src, float* __restrict__ csr_w) {
    int e = blockIdx.x * 256 + threadIdx.x;
    if (e < N_EDGES) {
        int p = ptr[dst[e]] + li[e];
        csr_src[p] = src[e];
        csr_w[p] = w[e];
    }
}

// dis = rsqrt(1 + row-sum of raw w)
__global__ void k_degsum(const int* __restrict__ ptr, const float* __restrict__ csr_w,
                         float* __restrict__ dis) {
    int v = blockIdx.x * 256 + threadIdx.x;
    if (v < N_NODES) {
        int p0 = ptr[v], p1 = ptr[v + 1];
        float s = 1.0f;
        for (int p = p0; p < p1; p++) s += csr_w[p];
        dis[v] = rsqrtf(s);
    }
}

// ---------- W1 transpose+cvt: wt[n][k] bf16 ----------

__global__ void k_prep_w1(const float* __restrict__ W1, unsigned short* __restrict__ wt) {
    int t = blockIdx.x * 256 + threadIdx.x;
    if (t < HID * IN_DIM) {
        int n = t >> 9, k = t & 511;
        wt[t] = f2bf(W1[(size_t)k * HID + n]);
    }
}

// ---------- layer 1 GEMM via bf16 MFMA: h1s = bf16(dis[row] * (x @ W1)) ----------

#define LDK 72

__global__ __launch_bounds__(256) void k_gemm1(const float* __restrict__ x,
                                               const unsigned short* __restrict__ wt,
                                               const float* __restrict__ dis,
                                               unsigned short* __restrict__ h1s) {
    __shared__ unsigned short xs[64][LDK];
    __shared__ unsigned short ws[64][LDK];

    int t = threadIdx.x;
    int row0 = blockIdx.x * 64;
    int wave = t >> 6, lane = t & 63;
    int lm = lane & 15, quad = lane >> 4;

    f32x4 acc[4];
#pragma unroll
    for (int nt = 0; nt < 4; nt++) acc[nt] = (f32x4)(0.f);

    for (int k0 = 0; k0 < IN_DIM; k0 += 64) {
        __syncthreads();
        {
            int c8 = (t & 7) * 8;
#pragma unroll
            for (int h = 0; h < 2; h++) {
                int r = (t >> 3) + h * 32;
                int gr = row0 + r;
                if (gr >= N_NODES) gr = N_NODES - 1;
                const float* xp = x + (size_t)gr * IN_DIM + k0 + c8;
                float4 v0 = *(const float4*)xp;
                float4 v1 = *(const float4*)(xp + 4);
                ushort8 pk;
                pk.s0 = f2bf(v0.x); pk.s1 = f2bf(v0.y); pk.s2 = f2bf(v0.z); pk.s3 = f2bf(v0.w);
                pk.s4 = f2bf(v1.x); pk.s5 = f2bf(v1.y); pk.s6 = f2bf(v1.z); pk.s7 = f2bf(v1.w);
                *(ushort8*)&xs[r][c8] = pk;
            }
        }
        {
            int n = t >> 2, kc = (t & 3) * 16;
            const unsigned short* wp = wt + (size_t)n * IN_DIM + k0 + kc;
            *(ushort8*)&ws[n][kc]     = *(const ushort8*)wp;
            *(ushort8*)&ws[n][kc + 8] = *(const ushort8*)(wp + 8);
        }
        __syncthreads();
#pragma unroll
        for (int kk = 0; kk < 64; kk += 32) {
            bf16x8 afrag = *(bf16x8*)&xs[wave * 16 + lm][kk + quad * 8];
#pragma unroll
            for (int nt = 0; nt < 4; nt++) {
                bf16x8 bfrag = *(bf16x8*)&ws[nt * 16 + lm][kk + quad * 8];
                acc[nt] = __builtin_amdgcn_mfma_f32_16x16x32_bf16(afrag, bfrag, acc[nt], 0, 0, 0);
            }
        }
    }
#pragma unroll
    for (int i = 0; i < 4; i++) {
        int gr = row0 + wave * 16 + quad * 4 + i;
        if (gr < N_NODES) {
            float dv = dis[gr];
#pragma unroll
            for (int nt = 0; nt < 4; nt++)
                h1s[(size_t)gr * HID + nt * 16 + lm] = f2bf(dv * acc[nt][i]);
        }
    }
}

// ---------- fused layer-1 aggregation + bias + relu + GEMM2 ----------
// wave per node. Edge loop: lane=(j 0..3, c 0..15), gathers ushort4 of h1s.
// After j-reduction every lane holds a1 dims [4c..4c+3]; 64x16 matvec with
// LDS-transposed W2 (pad 68); butterfly over c; write h2s bf16 (16 per node).

__global__ __launch_bounds__(256) void k_agg1(const unsigned short* __restrict__ h1s,
                                              const int* __restrict__ ptr,
                                              const int* __restrict__ csr_src,
                                              const float* __restrict__ csr_w,
                                              const float* __restrict__ dis,
                                              const float* __restrict__ b1,
                                              const float* __restrict__ W2,
                                              unsigned short* __restrict__ h2s) {
    __shared__ float w2t[NCLS * 68];   // w2t[cc][k] transposed, pad 68
    for (int i = threadIdx.x; i < HID * NCLS; i += 256) {
        int k = i >> 4, cc = i & 15;
        w2t[cc * 68 + k] = W2[i];
    }
    __syncthreads();

    int wave = threadIdx.x >> 6, lane = threadIdx.x & 63;
    int v = blockIdx.x * 4 + wave;
    if (v >= N_NODES) return;
    int j = lane >> 4, c = lane & 15;
    int p0 = ptr[v], p1 = ptr[v + 1];

    float a0 = 0.f, a1v = 0.f, a2 = 0.f, a3 = 0.f;
    for (int base = p0; base < p1; base += 8) {
#pragma unroll
        for (int half = 0; half < 2; half++) {
            int idx = base + half * 4 + j;
            bool valid = idx < p1;
            int s = valid ? csr_src[idx] : v;
            float wgt = valid ? csr_w[idx] : 0.f;
            ushort4 g = *(const ushort4*)&h1s[(size_t)s * HID + c * 4];
            a0 += wgt * bf2f(g.x);
            a1v += wgt * bf2f(g.y);
            a2 += wgt * bf2f(g.z);
            a3 += wgt * bf2f(g.w);
        }
    }
    // reduce across j (lane bits 4,5) — afterwards ALL lanes hold the sums for their c
#pragma unroll
    for (int m = 16; m <= 32; m <<= 1) {
        a0 += __shfl_xor(a0, m, 64);
        a1v += __shfl_xor(a1v, m, 64);
        a2 += __shfl_xor(a2, m, 64);
        a3 += __shfl_xor(a3, m, 64);
    }
    float dv = dis[v];
    ushort4 sv = *(const ushort4*)&h1s[(size_t)v * HID + c * 4];
    float4 bv = *(const float4*)&b1[c * 4];
    float r0 = dv * (a0 + bf2f(sv.x)) + bv.x;
    float r1 = dv * (a1v + bf2f(sv.y)) + bv.y;
    float r2 = dv * (a2 + bf2f(sv.z)) + bv.z;
    float r3 = dv * (a3 + bf2f(sv.w)) + bv.w;
    r0 = r0 > 0.f ? r0 : 0.f;
    r1 = r1 > 0.f ? r1 : 0.f;
    r2 = r2 > 0.f ? r2 : 0.f;
    r3 = r3 > 0.f ? r3 : 0.f;

    // matvec: partial[cc] = sum_i r_i * W2[4c+i][cc]
    float partial[NCLS];
#pragma unroll
    for (int cc = 0; cc < NCLS; cc++) {
        const float* wp = &w2t[cc * 68 + 4 * c];
        partial[cc] = r0 * wp[0] + r1 * wp[1] + r2 * wp[2] + r3 * wp[3];
    }
    // butterfly over c (lane bits 0..3): every lane ends with full h2[cc]
#pragma unroll
    for (int m = 1; m <= 8; m <<= 1)
#pragma unroll
        for (int cc = 0; cc < NCLS; cc++)
            partial[cc] += __shfl_xor(partial[cc], m, 16);

    if (lane < 16) {
        float sel = partial[0];
#pragma unroll
        for (int cc = 1; cc < NCLS; cc++) sel = (c == cc) ? partial[cc] : sel;
        h2s[(size_t)v * NCLS + c] = f2bf(dv * sel);
    }
}

// ---------- layer 2 aggregation + bias + log_softmax ----------
// wave per node, j=lane>>4 edge slot, c=lane&15 class

__global__ __launch_bounds__(256) void k_agg2(const unsigned short* __restrict__ h2s,
                                              const int* __restrict__ ptr,
                                              const int* __restrict__ csr_src,
                                              const float* __restrict__ csr_w,
                                              const float* __restrict__ dis,
                                              const float* __restrict__ b2,
                                              float* __restrict__ out) {
    int wave = threadIdx.x >> 6, lane = threadIdx.x & 63;
    int v = blockIdx.x * 4 + wave;
    if (v >= N_NODES) return;
    int j = lane >> 4, c = lane & 15;
    int p0 = ptr[v], p1 = ptr[v + 1];

    float acc = 0.f;
    for (int base = p0; base < p1; base += 8) {
#pragma unroll
        for (int half = 0; half < 2; half++) {
            int idx = base + half * 4 + j;
            bool valid = idx < p1;
            int s = valid ? csr_src[idx] : v;
            float wgt = valid ? csr_w[idx] : 0.f;
            acc += wgt * bf2f(h2s[(size_t)s * NCLS + c]);
        }
    }
#pragma unroll
    for (int m = 16; m <= 32; m <<= 1) acc += __shfl_xor(acc, m, 64);

    float dv = dis[v];
    float z = dv * (acc + bf2f(h2s[(size_t)v * NCLS + c])) + b2[c];

    float mx = z;
#pragma unroll
    for (int off = 8; off >= 1; off >>= 1) mx = fmaxf(mx, __shfl_xor(mx, off, 16));
    float e = expf(z - mx);
    float s = e;
#pragma unroll
    for (int off = 8; off >= 1; off >>= 1) s += __shfl_xor(s, off, 16);
    if (lane < 16) out[(size_t)v * NCLS + c] = z - mx - logf(s);
}

// ---------- launch ----------

extern "C" void kernel_launch(void* const* d_in, const int* in_sizes, int n_in,
                              void* d_out, int out_size, void* d_ws, size_t ws_size,
                              hipStream_t stream) {
    const float* x  = (const float*)d_in[0];
    const int*   ei = (const int*)d_in[1];
    const float* w  = (const float*)d_in[2];
    const float* W1 = (const float*)d_in[3];
    const float* b1 = (const float*)d_in[4];
    const float* W2 = (const float*)d_in[5];
    const float* b2 = (const float*)d_in[6];
    const int* src = ei;               // edge_index[0]
    const int* dst = ei + N_EDGES;     // edge_index[1]

    char* wsb = (char*)d_ws;
    size_t off = 0;
    auto alloc = [&](size_t bytes) {
        void* p = wsb + off;
        off += (bytes + 255) & ~(size_t)255;
        return p;
    };
    int*   cnt   = (int*)  alloc((size_t)N_NODES * 4);
    int*   li    = (int*)  alloc((size_t)N_EDGES * 4);
    int*   ptr   = (int*)  alloc((size_t)(N_NODES + 1) * 4);
    int*   bsum  = (int*)  alloc((size_t)NB * 4);
    int*   csr_s = (int*)  alloc((size_t)N_EDGES * 4);
    float* csr_w = (float*)alloc((size_t)N_EDGES * 4);
    float* dis   = (float*)alloc((size_t)N_NODES * 4);
    unsigned short* h1s = (unsigned short*)alloc((size_t)N_NODES * HID * 2);
    unsigned short* h2s = (unsigned short*)alloc((size_t)N_NODES * NCLS * 2);
    unsigned short* wt  = (unsigned short*)alloc((size_t)HID * IN_DIM * 2);

    float* outp = (float*)d_out;

    k_init   <<<(N_NODES + 255) / 256, 256, 0, stream>>>(cnt);
    k_pass1  <<<(N_EDGES + 255) / 256, 256, 0, stream>>>(dst, cnt, li);
    k_scan1  <<<NB, 256, 0, stream>>>(cnt, ptr, bsum);
    k_scan2  <<<1, 128, 0, stream>>>(bsum, ptr);
    k_scan3  <<<NB, 256, 0, stream>>>(ptr, bsum);
    k_pass2  <<<(N_EDGES + 255) / 256, 256, 0, stream>>>(src, dst, w, ptr, li, csr_s, csr_w);
    k_degsum <<<(N_NODES + 255) / 256, 256, 0, stream>>>(ptr, csr_w, dis);
    k_prep_w1<<<(HID * IN_DIM + 255) / 256, 256, 0, stream>>>(W1, wt);
    k_gemm1  <<<(N_NODES + 63) / 64, 256, 0, stream>>>(x, wt, dis, h1s);
    k_agg1   <<<(N_NODES + 3) / 4, 256, 0, stream>>>(h1s, ptr, csr_s, csr_w, dis, b1, W2, h2s);
    k_agg2   <<<(N_NODES + 3) / 4, 256, 0, stream>>>(h2s, ptr, csr_s, csr_w, dis, b2, outp);
}

// Round 5
// 553.699 us; speedup vs baseline: 1.1219x; 1.1219x over previous
//
#include <hip/hip_runtime.h>
#include <hip/hip_bf16.h>

#define N_NODES 100000
#define N_EDGES 1600000
#define IN_DIM 512
#define HID 64
#define NCLS 16
#define NB ((N_NODES + 1023) / 1024)   // scan blocks (98)

typedef __attribute__((ext_vector_type(8))) short bf16x8;
typedef __attribute__((ext_vector_type(8))) unsigned short ushort8;
typedef __attribute__((ext_vector_type(4))) float f32x4;

static __device__ __forceinline__ unsigned short f2bf(float f) {
    union { float f; unsigned int u; } v; v.f = f;
    unsigned int u = v.u;
    unsigned int r = (u + 0x7fffu + ((u >> 16) & 1u)) >> 16;
    return (unsigned short)r;
}
static __device__ __forceinline__ float bf2f(unsigned short u) {
    union { unsigned int i; float f; } v; v.i = ((unsigned int)u) << 16; return v.f;
}

// ---------- graph preprocessing ----------

__global__ void k_init(int* cnt) {
    int i = blockIdx.x * 256 + threadIdx.x;
    if (i < N_NODES) cnt[i] = 0;
}

// one atomic per edge: slot within the dst row
__global__ void k_pass1(const int* __restrict__ dst, int* cnt, int* __restrict__ li) {
    int e = blockIdx.x * 256 + threadIdx.x;
    if (e < N_EDGES) li[e] = atomicAdd(&cnt[dst[e]], 1);
}

// exclusive scan of cnt -> ptr
__global__ void k_scan1(const int* __restrict__ cnt, int* ptr, int* bsum) {
    __shared__ int s[256];
    int t = threadIdx.x;
    int i0 = blockIdx.x * 1024 + t * 4;
    int c[4];
#pragma unroll
    for (int j = 0; j < 4; j++) c[j] = (i0 + j < N_NODES) ? cnt[i0 + j] : 0;
    int sum4 = c[0] + c[1] + c[2] + c[3];
    s[t] = sum4;
    __syncthreads();
    int v = sum4;
    for (int off = 1; off < 256; off <<= 1) {
        int add = (t >= off) ? s[t - off] : 0;
        __syncthreads();
        v += add;
        s[t] = v;
        __syncthreads();
    }
    int run = v - sum4;
#pragma unroll
    for (int j = 0; j < 4; j++) {
        if (i0 + j < N_NODES) ptr[i0 + j] = run;
        run += c[j];
    }
    if (t == 255) bsum[blockIdx.x] = v;
}

__global__ void k_scan2(int* bsum, int* ptr) {
    __shared__ int s[128];
    int t = threadIdx.x;
    int val = (t < NB) ? bsum[t] : 0;
    s[t] = val;
    __syncthreads();
    int v = val;
    for (int off = 1; off < 128; off <<= 1) {
        int add = (t >= off) ? s[t - off] : 0;
        __syncthreads();
        v += add;
        s[t] = v;
        __syncthreads();
    }
    if (t < NB) bsum[t] = v - val;
    if (t == 0) ptr[N_NODES] = N_EDGES;
}

__global__ void k_scan3(int* ptr, const int* __restrict__ bsum) {
    int t = threadIdx.x;
    int i0 = blockIdx.x * 1024 + t * 4;
    int add = bsum[blockIdx.x];
#pragma unroll
    for (int j = 0; j < 4; j++)
        if (i0 + j < N_NODES) ptr[i0 + j] += add;
}

// atomic-free scatter: position = ptr[dst] + li[e]; csr_w holds RAW w
__global__ void k_pass2(const int* __restrict__ src, const int* __restrict__ dst,
                        const float* __restrict__ w, const int* __restrict__ ptr,
                        const int* __restrict__ li,
                        int* __restrict__ csr_src, float* __restrict__ csr_w) {
    int e = blockIdx.x * 256 + threadIdx.x;
    if (e < N_EDGES) {
        int p = ptr[dst[e]] + li[e];
        csr_src[p] = src[e];
        csr_w[p] = w[e];
    }
}

// dis = rsqrt(1 + row-sum of raw w)
__global__ void k_degsum(const int* __restrict__ ptr, const float* __restrict__ csr_w,
                         float* __restrict__ dis) {
    int v = blockIdx.x * 256 + threadIdx.x;
    if (v < N_NODES) {
        int p0 = ptr[v], p1 = ptr[v + 1];
        float s = 1.0f;
        for (int p = p0; p < p1; p++) s += csr_w[p];
        dis[v] = rsqrtf(s);
    }
}

// ---------- W1 transpose+cvt: wt[n][k] bf16 ----------

__global__ void k_prep_w1(const float* __restrict__ W1, unsigned short* __restrict__ wt) {
    int t = blockIdx.x * 256 + threadIdx.x;
    if (t < HID * IN_DIM) {
        int n = t >> 9, k = t & 511;
        wt[t] = f2bf(W1[(size_t)k * HID + n]);
    }
}

// ---------- layer 1 GEMM via bf16 MFMA: h1s = bf16(dis[row] * (x @ W1)) ----------

#define LDK 72

__global__ __launch_bounds__(256) void k_gemm1(const float* __restrict__ x,
                                               const unsigned short* __restrict__ wt,
                                               const float* __restrict__ dis,
                                               unsigned short* __restrict__ h1s) {
    __shared__ unsigned short xs[64][LDK];
    __shared__ unsigned short ws[64][LDK];

    int t = threadIdx.x;
    int row0 = blockIdx.x * 64;
    int wave = t >> 6, lane = t & 63;
    int lm = lane & 15, quad = lane >> 4;

    f32x4 acc[4];
#pragma unroll
    for (int nt = 0; nt < 4; nt++) acc[nt] = (f32x4)(0.f);

    for (int k0 = 0; k0 < IN_DIM; k0 += 64) {
        __syncthreads();
        {
            int c8 = (t & 7) * 8;
#pragma unroll
            for (int h = 0; h < 2; h++) {
                int r = (t >> 3) + h * 32;
                int gr = row0 + r;
                if (gr >= N_NODES) gr = N_NODES - 1;
                const float* xp = x + (size_t)gr * IN_DIM + k0 + c8;
                float4 v0 = *(const float4*)xp;
                float4 v1 = *(const float4*)(xp + 4);
                ushort8 pk;
                pk.s0 = f2bf(v0.x); pk.s1 = f2bf(v0.y); pk.s2 = f2bf(v0.z); pk.s3 = f2bf(v0.w);
                pk.s4 = f2bf(v1.x); pk.s5 = f2bf(v1.y); pk.s6 = f2bf(v1.z); pk.s7 = f2bf(v1.w);
                *(ushort8*)&xs[r][c8] = pk;
            }
        }
        {
            int n = t >> 2, kc = (t & 3) * 16;
            const unsigned short* wp = wt + (size_t)n * IN_DIM + k0 + kc;
            *(ushort8*)&ws[n][kc]     = *(const ushort8*)wp;
            *(ushort8*)&ws[n][kc + 8] = *(const ushort8*)(wp + 8);
        }
        __syncthreads();
#pragma unroll
        for (int kk = 0; kk < 64; kk += 32) {
            bf16x8 afrag = *(bf16x8*)&xs[wave * 16 + lm][kk + quad * 8];
#pragma unroll
            for (int nt = 0; nt < 4; nt++) {
                bf16x8 bfrag = *(bf16x8*)&ws[nt * 16 + lm][kk + quad * 8];
                acc[nt] = __builtin_amdgcn_mfma_f32_16x16x32_bf16(afrag, bfrag, acc[nt], 0, 0, 0);
            }
        }
    }
#pragma unroll
    for (int i = 0; i < 4; i++) {
        int gr = row0 + wave * 16 + quad * 4 + i;
        if (gr < N_NODES) {
            float dv = dis[gr];
#pragma unroll
            for (int nt = 0; nt < 4; nt++)
                h1s[(size_t)gr * HID + nt * 16 + lm] = f2bf(dv * acc[nt][i]);
        }
    }
}

// ---------- layer 1 aggregation + bias + relu -> a1s bf16 ----------
// thread per (node, dim-quad): v=t>>4, c=t&15. Each lane owns 4 dims, loops
// over ALL edges of v with a 4-deep independent unroll -> 4 nodes/wave x 4
// gathers in flight = 16 outstanding row-gathers per wave. No shuffles.

__global__ __launch_bounds__(256) void k_agg1(const unsigned short* __restrict__ h1s,
                                              const int* __restrict__ ptr,
                                              const int* __restrict__ csr_src,
                                              const float* __restrict__ csr_w,
                                              const float* __restrict__ dis,
                                              const float* __restrict__ b1,
                                              unsigned short* __restrict__ a1s) {
    int t = blockIdx.x * 256 + threadIdx.x;
    int v = t >> 4, c = t & 15;
    if (v >= N_NODES) return;
    int p0 = ptr[v], p1 = ptr[v + 1];

    float a0 = 0.f, a1v = 0.f, a2 = 0.f, a3 = 0.f;
    for (int base = p0; base < p1; base += 4) {
#pragma unroll
        for (int u = 0; u < 4; u++) {
            int idx = base + u;
            bool valid = idx < p1;
            int s = valid ? csr_src[idx] : v;      // broadcast across the 16 lanes of v
            float wgt = valid ? csr_w[idx] : 0.f;
            ushort4 g = *(const ushort4*)&h1s[(size_t)s * HID + c * 4];
            a0 += wgt * bf2f(g.x);
            a1v += wgt * bf2f(g.y);
            a2 += wgt * bf2f(g.z);
            a3 += wgt * bf2f(g.w);
        }
    }
    float dv = dis[v];
    ushort4 sv = *(const ushort4*)&h1s[(size_t)v * HID + c * 4];
    float4 bv = *(const float4*)&b1[c * 4];
    float r0 = dv * (a0 + bf2f(sv.x)) + bv.x;
    float r1 = dv * (a1v + bf2f(sv.y)) + bv.y;
    float r2 = dv * (a2 + bf2f(sv.z)) + bv.z;
    float r3 = dv * (a3 + bf2f(sv.w)) + bv.w;
    ushort4 o;
    o.x = f2bf(r0 > 0.f ? r0 : 0.f);
    o.y = f2bf(r1 > 0.f ? r1 : 0.f);
    o.z = f2bf(r2 > 0.f ? r2 : 0.f);
    o.w = f2bf(r3 > 0.f ? r3 : 0.f);
    *(ushort4*)&a1s[(size_t)v * HID + c * 4] = o;
}

// ---------- layer 2 GEMM: h2s = bf16(dis[v] * (a1 @ W2)) ----------
// thread per (node, class); W2 in LDS; row reads L1-shared across 16 lanes.

__global__ __launch_bounds__(256) void k_gemm2(const unsigned short* __restrict__ a1s,
                                               const float* __restrict__ W2,
                                               const float* __restrict__ dis,
                                               unsigned short* __restrict__ h2s) {
    __shared__ float ws[HID * NCLS];
    for (int i = threadIdx.x; i < HID * NCLS; i += 256) ws[i] = W2[i];
    __syncthreads();
    int t = blockIdx.x * 256 + threadIdx.x;
    int v = t >> 4, cc = t & 15;
    if (v >= N_NODES) return;
    const unsigned short* row = a1s + (size_t)v * HID;
    float acc = 0.f;
#pragma unroll
    for (int k = 0; k < HID; k += 4) {
        ushort4 av = *(const ushort4*)(row + k);
        acc = fmaf(bf2f(av.x), ws[(k + 0) * NCLS + cc], acc);
        acc = fmaf(bf2f(av.y), ws[(k + 1) * NCLS + cc], acc);
        acc = fmaf(bf2f(av.z), ws[(k + 2) * NCLS + cc], acc);
        acc = fmaf(bf2f(av.w), ws[(k + 3) * NCLS + cc], acc);
    }
    h2s[(size_t)v * NCLS + cc] = f2bf(dis[v] * acc);
}

// ---------- layer 2 aggregation + bias + log_softmax ----------
// thread per (node, class), 4-deep edge unroll -> 4 nodes/wave x 4 in flight.

__global__ __launch_bounds__(256) void k_agg2(const unsigned short* __restrict__ h2s,
                                              const int* __restrict__ ptr,
                                              const int* __restrict__ csr_src,
                                              const float* __restrict__ csr_w,
                                              const float* __restrict__ dis,
                                              const float* __restrict__ b2,
                                              float* __restrict__ out) {
    int t = blockIdx.x * 256 + threadIdx.x;
    int v = t >> 4, c = t & 15;
    if (v >= N_NODES) return;
    int p0 = ptr[v], p1 = ptr[v + 1];

    float acc = 0.f;
    for (int base = p0; base < p1; base += 4) {
#pragma unroll
        for (int u = 0; u < 4; u++) {
            int idx = base + u;
            bool valid = idx < p1;
            int s = valid ? csr_src[idx] : v;
            float wgt = valid ? csr_w[idx] : 0.f;
            acc += wgt * bf2f(h2s[(size_t)s * NCLS + c]);
        }
    }
    float dv = dis[v];
    float z = dv * (acc + bf2f(h2s[(size_t)v * NCLS + c])) + b2[c];

    float mx = z;
#pragma unroll
    for (int off = 8; off >= 1; off >>= 1) mx = fmaxf(mx, __shfl_xor(mx, off, 16));
    float e = expf(z - mx);
    float s = e;
#pragma unroll
    for (int off = 8; off >= 1; off >>= 1) s += __shfl_xor(s, off, 16);
    out[(size_t)v * NCLS + c] = z - mx - logf(s);
}

// ---------- launch ----------

extern "C" void kernel_launch(void* const* d_in, const int* in_sizes, int n_in,
                              void* d_out, int out_size, void* d_ws, size_t ws_size,
                              hipStream_t stream) {
    const float* x  = (const float*)d_in[0];
    const int*   ei = (const int*)d_in[1];
    const float* w  = (const float*)d_in[2];
    const float* W1 = (const float*)d_in[3];
    const float* b1 = (const float*)d_in[4];
    const float* W2 = (const float*)d_in[5];
    const float* b2 = (const float*)d_in[6];
    const int* src = ei;               // edge_index[0]
    const int* dst = ei + N_EDGES;     // edge_index[1]

    char* wsb = (char*)d_ws;
    size_t off = 0;
    auto alloc = [&](size_t bytes) {
        void* p = wsb + off;
        off += (bytes + 255) & ~(size_t)255;
        return p;
    };
    int*   cnt   = (int*)  alloc((size_t)N_NODES * 4);
    int*   li    = (int*)  alloc((size_t)N_EDGES * 4);
    int*   ptr   = (int*)  alloc((size_t)(N_NODES + 1) * 4);
    int*   bsum  = (int*)  alloc((size_t)NB * 4);
    int*   csr_s = (int*)  alloc((size_t)N_EDGES * 4);
    float* csr_w = (float*)alloc((size_t)N_EDGES * 4);
    float* dis   = (float*)alloc((size_t)N_NODES * 4);
    unsigned short* h1s = (unsigned short*)alloc((size_t)N_NODES * HID * 2);
    unsigned short* a1s = (unsigned short*)alloc((size_t)N_NODES * HID * 2);
    unsigned short* h2s = (unsigned short*)alloc((size_t)N_NODES * NCLS * 2);
    unsigned short* wt  = (unsigned short*)alloc((size_t)HID * IN_DIM * 2);

    float* outp = (float*)d_out;

    k_init   <<<(N_NODES + 255) / 256, 256, 0, stream>>>(cnt);
    k_pass1  <<<(N_EDGES + 255) / 256, 256, 0, stream>>>(dst, cnt, li);
    k_scan1  <<<NB, 256, 0, stream>>>(cnt, ptr, bsum);
    k_scan2  <<<1, 128, 0, stream>>>(bsum, ptr);
    k_scan3  <<<NB, 256, 0, stream>>>(ptr, bsum);
    k_pass2  <<<(N_EDGES + 255) / 256, 256, 0, stream>>>(src, dst, w, ptr, li, csr_s, csr_w);
    k_degsum <<<(N_NODES + 255) / 256, 256, 0, stream>>>(ptr, csr_w, dis);
    k_prep_w1<<<(HID * IN_DIM + 255) / 256, 256, 0, stream>>>(W1, wt);
    k_gemm1  <<<(N_NODES + 63) / 64, 256, 0, stream>>>(x, wt, dis, h1s);
    k_agg1   <<<(N_NODES * 16 + 255) / 256, 256, 0, stream>>>(h1s, ptr, csr_s, csr_w, dis, b1, a1s);
    k_gemm2  <<<(N_NODES * 16 + 255) / 256, 256, 0, stream>>>(a1s, W2, dis, h2s);
    k_agg2   <<<(N_NODES * 16 + 255) / 256, 256, 0, stream>>>(h2s, ptr, csr_s, csr_w, dis, b2, outp);
}

// Round 6
// 491.901 us; speedup vs baseline: 1.2628x; 1.1256x over previous
//
#include <hip/hip_runtime.h>
#include <hip/hip_bf16.h>

#define N_NODES 100000
#define N_EDGES 1600000
#define IN_DIM 512
#define HID 64
#define NCLS 16
#define NB ((N_NODES + 1023) / 1024)   // scan blocks (98)

#define GEMM_BLOCKS ((N_NODES + 63) / 64)          // 1563
#define PASS_BLOCKS ((N_EDGES + 255) / 256)        // 6250
#define FUSED_GRID (GEMM_BLOCKS + PASS_BLOCKS)     // 7813

typedef __attribute__((ext_vector_type(8))) short bf16x8;
typedef __attribute__((ext_vector_type(8))) unsigned short ushort8;
typedef __attribute__((ext_vector_type(4))) float f32x4;

static __device__ __forceinline__ unsigned short f2bf(float f) {
    union { float f; unsigned int u; } v; v.f = f;
    unsigned int u = v.u;
    unsigned int r = (u + 0x7fffu + ((u >> 16) & 1u)) >> 16;
    return (unsigned short)r;
}
static __device__ __forceinline__ float bf2f(unsigned short u) {
    union { unsigned int i; float f; } v; v.i = ((unsigned int)u) << 16; return v.f;
}
static __device__ __forceinline__ unsigned int f2bf2u(float a, float b) {
    union { __hip_bfloat162 h; unsigned int u; } cv;
    cv.h = __float22bfloat162_rn(make_float2(a, b));   // packed RNE cvt
    return cv.u;
}

// ---------- setup: zero cnt + transpose/cvt W1 -> wt[n][k] bf16 ----------

__global__ void k_setup(int* cnt, const float* __restrict__ W1,
                        unsigned short* __restrict__ wt) {
    int t = blockIdx.x * 256 + threadIdx.x;
    if (t < N_NODES) cnt[t] = 0;
    int j = t - N_NODES;
    if (j >= 0 && j < HID * IN_DIM) {
        int n = j >> 9, k = j & 511;
        wt[j] = f2bf(W1[(size_t)k * HID + n]);
    }
}

// ---------- fused: pass1 (histogram+slot atomics) | gemm1 (MFMA) ----------
// Interleaved roles 1:4 so both kinds co-reside on every CU: atomic-latency
// waves hide under GEMM streaming (m114: co-scheduled pipes, time ~= max).

#define LDK 72

__global__ __launch_bounds__(256) void k_fused(const int* __restrict__ dst,
                                               int* cnt, int* __restrict__ li,
                                               const float* __restrict__ x,
                                               const unsigned short* __restrict__ wt,
                                               unsigned short* __restrict__ h1s) {
    __shared__ unsigned short xs[64][LDK];
    __shared__ unsigned short ws[64][LDK];

    int b = blockIdx.x;
    int q = b / 5, r = b % 5;
    if (r != 0) {
        // ---- pass1 role ----
        int pid = q * 4 + r - 1;                  // 0..6249
        int e = pid * 256 + threadIdx.x;
        if (e < N_EDGES) li[e] = atomicAdd(&cnt[dst[e]], 1);
        return;
    }
    // ---- gemm1 role: h1s = bf16(x @ W1), rows [gid*64, gid*64+64) ----
    int gid = q;                                   // 0..1562
    int t = threadIdx.x;
    int row0 = gid * 64;
    int wave = t >> 6, lane = t & 63;
    int lm = lane & 15, quad = lane >> 4;

    f32x4 acc[4];
#pragma unroll
    for (int nt = 0; nt < 4; nt++) acc[nt] = (f32x4)(0.f);

    for (int k0 = 0; k0 < IN_DIM; k0 += 64) {
        __syncthreads();
        {
            int c8 = (t & 7) * 8;
#pragma unroll
            for (int h = 0; h < 2; h++) {
                int rr = (t >> 3) + h * 32;
                int gr = row0 + rr;
                if (gr >= N_NODES) gr = N_NODES - 1;
                const float* xp = x + (size_t)gr * IN_DIM + k0 + c8;
                float4 v0 = *(const float4*)xp;
                float4 v1 = *(const float4*)(xp + 4);
                union { ushort8 s; unsigned int u[4]; } pk;
                pk.u[0] = f2bf2u(v0.x, v0.y);
                pk.u[1] = f2bf2u(v0.z, v0.w);
                pk.u[2] = f2bf2u(v1.x, v1.y);
                pk.u[3] = f2bf2u(v1.z, v1.w);
                *(ushort8*)&xs[rr][c8] = pk.s;
            }
        }
        {
            int n = t >> 2, kc = (t & 3) * 16;
            const unsigned short* wp = wt + (size_t)n * IN_DIM + k0 + kc;
            *(ushort8*)&ws[n][kc]     = *(const ushort8*)wp;
            *(ushort8*)&ws[n][kc + 8] = *(const ushort8*)(wp + 8);
        }
        __syncthreads();
#pragma unroll
        for (int kk = 0; kk < 64; kk += 32) {
            bf16x8 afrag = *(bf16x8*)&xs[wave * 16 + lm][kk + quad * 8];
#pragma unroll
            for (int nt = 0; nt < 4; nt++) {
                bf16x8 bfrag = *(bf16x8*)&ws[nt * 16 + lm][kk + quad * 8];
                acc[nt] = __builtin_amdgcn_mfma_f32_16x16x32_bf16(afrag, bfrag, acc[nt], 0, 0, 0);
            }
        }
    }
#pragma unroll
    for (int i = 0; i < 4; i++) {
        int gr = row0 + wave * 16 + quad * 4 + i;
        if (gr < N_NODES) {
#pragma unroll
            for (int nt = 0; nt < 4; nt++)
                h1s[(size_t)gr * HID + nt * 16 + lm] = f2bf(acc[nt][i]);
        }
    }
}

// ---------- scans: exclusive scan of cnt -> ptr ----------

__global__ void k_scan1(const int* __restrict__ cnt, int* ptr, int* bsum) {
    __shared__ int s[256];
    int t = threadIdx.x;
    int i0 = blockIdx.x * 1024 + t * 4;
    int c[4];
#pragma unroll
    for (int j = 0; j < 4; j++) c[j] = (i0 + j < N_NODES) ? cnt[i0 + j] : 0;
    int sum4 = c[0] + c[1] + c[2] + c[3];
    s[t] = sum4;
    __syncthreads();
    int v = sum4;
    for (int off = 1; off < 256; off <<= 1) {
        int add = (t >= off) ? s[t - off] : 0;
        __syncthreads();
        v += add;
        s[t] = v;
        __syncthreads();
    }
    int run = v - sum4;
#pragma unroll
    for (int j = 0; j < 4; j++) {
        if (i0 + j < N_NODES) ptr[i0 + j] = run;
        run += c[j];
    }
    if (t == 255) bsum[blockIdx.x] = v;
}

__global__ void k_scan2(int* bsum, int* ptr) {
    __shared__ int s[128];
    int t = threadIdx.x;
    int val = (t < NB) ? bsum[t] : 0;
    s[t] = val;
    __syncthreads();
    int v = val;
    for (int off = 1; off < 128; off <<= 1) {
        int add = (t >= off) ? s[t - off] : 0;
        __syncthreads();
        v += add;
        s[t] = v;
        __syncthreads();
    }
    if (t < NB) bsum[t] = v - val;
    if (t == 0) ptr[N_NODES] = N_EDGES;
}

__global__ void k_scan3(int* ptr, const int* __restrict__ bsum) {
    int t = threadIdx.x;
    int i0 = blockIdx.x * 1024 + t * 4;
    int add = bsum[blockIdx.x];
#pragma unroll
    for (int j = 0; j < 4; j++)
        if (i0 + j < N_NODES) ptr[i0 + j] += add;
}

// ---------- pass2: atomic-free scatter of packed {src, raw w} ----------

__global__ void k_pass2(const int* __restrict__ src, const int* __restrict__ dst,
                        const float* __restrict__ w, const int* __restrict__ ptr,
                        const int* __restrict__ li, int2* __restrict__ csr) {
    int e = blockIdx.x * 256 + threadIdx.x;
    if (e < N_EDGES) {
        int p = ptr[dst[e]] + li[e];
        csr[p] = make_int2(src[e], __float_as_int(w[e]));
    }
}

// ---------- dis = rsqrt(1 + row-sum of raw w) ----------

__global__ void k_degsum(const int* __restrict__ ptr, const int2* __restrict__ csr,
                         float* __restrict__ dis) {
    int v = blockIdx.x * 256 + threadIdx.x;
    if (v < N_NODES) {
        int p0 = ptr[v], p1 = ptr[v + 1];
        float s = 1.0f;
        for (int p = p0; p < p1; p++) s += __int_as_float(csr[p].y);
        dis[v] = rsqrtf(s);
    }
}

// ---------- layer 1 aggregation + bias + relu -> a1s bf16 ----------
// thread per (node, dim-quad); 8-deep unroll -> 32 row-gathers in flight/wave.
// dis[src] gathered per edge (400 KB L2-resident, broadcast across 16 lanes).

__global__ __launch_bounds__(256) void k_agg1(const unsigned short* __restrict__ h1s,
                                              const int* __restrict__ ptr,
                                              const int2* __restrict__ csr,
                                              const float* __restrict__ dis,
                                              const float* __restrict__ b1,
                                              unsigned short* __restrict__ a1s) {
    int t = blockIdx.x * 256 + threadIdx.x;
    int v = t >> 4, c = t & 15;
    if (v >= N_NODES) return;
    int p0 = ptr[v], p1 = ptr[v + 1];

    float a0 = 0.f, a1v = 0.f, a2 = 0.f, a3 = 0.f;
    for (int base = p0; base < p1; base += 8) {
#pragma unroll
        for (int u = 0; u < 8; u++) {
            int idx = base + u;
            bool valid = idx < p1;
            int2 cw = valid ? csr[idx] : make_int2(v, 0);
            int s = cw.x;
            float wgt = __int_as_float(cw.y) * dis[s];
            ushort4 g = *(const ushort4*)&h1s[(size_t)s * HID + c * 4];
            a0 += wgt * bf2f(g.x);
            a1v += wgt * bf2f(g.y);
            a2 += wgt * bf2f(g.z);
            a3 += wgt * bf2f(g.w);
        }
    }
    float dv = dis[v], dvv = dv * dv;
    ushort4 sv = *(const ushort4*)&h1s[(size_t)v * HID + c * 4];
    float4 bv = *(const float4*)&b1[c * 4];
    float r0 = dv * a0 + dvv * bf2f(sv.x) + bv.x;
    float r1 = dv * a1v + dvv * bf2f(sv.y) + bv.y;
    float r2 = dv * a2 + dvv * bf2f(sv.z) + bv.z;
    float r3 = dv * a3 + dvv * bf2f(sv.w) + bv.w;
    ushort4 o;
    o.x = f2bf(r0 > 0.f ? r0 : 0.f);
    o.y = f2bf(r1 > 0.f ? r1 : 0.f);
    o.z = f2bf(r2 > 0.f ? r2 : 0.f);
    o.w = f2bf(r3 > 0.f ? r3 : 0.f);
    *(ushort4*)&a1s[(size_t)v * HID + c * 4] = o;
}

// ---------- layer 2 GEMM: h2s = bf16(a1 @ W2) (no dis fold) ----------

__global__ __launch_bounds__(256) void k_gemm2(const unsigned short* __restrict__ a1s,
                                               const float* __restrict__ W2,
                                               unsigned short* __restrict__ h2s) {
    __shared__ float ws[HID * NCLS];
    for (int i = threadIdx.x; i < HID * NCLS; i += 256) ws[i] = W2[i];
    __syncthreads();
    int t = blockIdx.x * 256 + threadIdx.x;
    int v = t >> 4, cc = t & 15;
    if (v >= N_NODES) return;
    const unsigned short* row = a1s + (size_t)v * HID;
    float acc = 0.f;
#pragma unroll
    for (int k = 0; k < HID; k += 4) {
        ushort4 av = *(const ushort4*)(row + k);
        acc = fmaf(bf2f(av.x), ws[(k + 0) * NCLS + cc], acc);
        acc = fmaf(bf2f(av.y), ws[(k + 1) * NCLS + cc], acc);
        acc = fmaf(bf2f(av.z), ws[(k + 2) * NCLS + cc], acc);
        acc = fmaf(bf2f(av.w), ws[(k + 3) * NCLS + cc], acc);
    }
    h2s[(size_t)v * NCLS + cc] = f2bf(acc);
}

// ---------- layer 2 aggregation + bias + log_softmax ----------

__global__ __launch_bounds__(256) void k_agg2(const unsigned short* __restrict__ h2s,
                                              const int* __restrict__ ptr,
                                              const int2* __restrict__ csr,
                                              const float* __restrict__ dis,
                                              const float* __restrict__ b2,
                                              float* __restrict__ out) {
    int t = blockIdx.x * 256 + threadIdx.x;
    int v = t >> 4, c = t & 15;
    if (v >= N_NODES) return;
    int p0 = ptr[v], p1 = ptr[v + 1];

    float acc = 0.f;
    for (int base = p0; base < p1; base += 8) {
#pragma unroll
        for (int u = 0; u < 8; u++) {
            int idx = base + u;
            bool valid = idx < p1;
            int2 cw = valid ? csr[idx] : make_int2(v, 0);
            int s = cw.x;
            float wgt = __int_as_float(cw.y) * dis[s];
            acc += wgt * bf2f(h2s[(size_t)s * NCLS + c]);
        }
    }
    float dv = dis[v], dvv = dv * dv;
    float z = dv * acc + dvv * bf2f(h2s[(size_t)v * NCLS + c]) + b2[c];

    float mx = z;
#pragma unroll
    for (int off = 8; off >= 1; off >>= 1) mx = fmaxf(mx, __shfl_xor(mx, off, 16));
    float e = expf(z - mx);
    float s = e;
#pragma unroll
    for (int off = 8; off >= 1; off >>= 1) s += __shfl_xor(s, off, 16);
    out[(size_t)v * NCLS + c] = z - mx - logf(s);
}

// ---------- launch ----------

extern "C" void kernel_launch(void* const* d_in, const int* in_sizes, int n_in,
                              void* d_out, int out_size, void* d_ws, size_t ws_size,
                              hipStream_t stream) {
    const float* x  = (const float*)d_in[0];
    const int*   ei = (const int*)d_in[1];
    const float* w  = (const float*)d_in[2];
    const float* W1 = (const float*)d_in[3];
    const float* b1 = (const float*)d_in[4];
    const float* W2 = (const float*)d_in[5];
    const float* b2 = (const float*)d_in[6];
    const int* src = ei;               // edge_index[0]
    const int* dst = ei + N_EDGES;     // edge_index[1]

    char* wsb = (char*)d_ws;
    size_t off = 0;
    auto alloc = [&](size_t bytes) {
        void* p = wsb + off;
        off += (bytes + 255) & ~(size_t)255;
        return p;
    };
    int*   cnt   = (int*)  alloc((size_t)N_NODES * 4);
    int*   li    = (int*)  alloc((size_t)N_EDGES * 4);
    int*   ptr   = (int*)  alloc((size_t)(N_NODES + 1) * 4);
    int*   bsum  = (int*)  alloc((size_t)NB * 4);
    int2*  csr   = (int2*) alloc((size_t)N_EDGES * 8);
    float* dis   = (float*)alloc((size_t)N_NODES * 4);
    unsigned short* h1s = (unsigned short*)alloc((size_t)N_NODES * HID * 2);
    unsigned short* a1s = (unsigned short*)alloc((size_t)N_NODES * HID * 2);
    unsigned short* h2s = (unsigned short*)alloc((size_t)N_NODES * NCLS * 2);
    unsigned short* wt  = (unsigned short*)alloc((size_t)HID * IN_DIM * 2);

    float* outp = (float*)d_out;

    k_setup  <<<(N_NODES + HID * IN_DIM + 255) / 256, 256, 0, stream>>>(cnt, W1, wt);
    k_fused  <<<FUSED_GRID, 256, 0, stream>>>(dst, cnt, li, x, wt, h1s);
    k_scan1  <<<NB, 256, 0, stream>>>(cnt, ptr, bsum);
    k_scan2  <<<1, 128, 0, stream>>>(bsum, ptr);
    k_scan3  <<<NB, 256, 0, stream>>>(ptr, bsum);
    k_pass2  <<<PASS_BLOCKS, 256, 0, stream>>>(src, dst, w, ptr, li, csr);
    k_degsum <<<(N_NODES + 255) / 256, 256, 0, stream>>>(ptr, csr, dis);
    k_agg1   <<<(N_NODES * 16 + 255) / 256, 256, 0, stream>>>(h1s, ptr, csr, dis, b1, a1s);
    k_gemm2  <<<(N_NODES * 16 + 255) / 256, 256, 0, stream>>>(a1s, W2, h2s);
    k_agg2   <<<(N_NODES * 16 + 255) / 256, 256, 0, stream>>>(h2s, ptr, csr, dis, b2, outp);
}